// Round 9
// baseline (164.620 us; speedup 1.0000x reference)
//
#include <hip/hip_runtime.h>

#define NN   6144
#define EE   98304
#define DIN  128
#define DD   256
#define TT   32
#define NH   4
#define ATTN_Z 6
#define WROWS 3328   // 256 wcat + 2*(768+256+256+256)

typedef __attribute__((ext_vector_type(8))) short short8;
typedef __attribute__((ext_vector_type(4))) float f32x4;
typedef unsigned short u16;

__device__ __forceinline__ float bf2f(u16 u) {
    return __uint_as_float(((unsigned)u) << 16);
}
__device__ __forceinline__ u16 f2bf(float f) {
    unsigned u = __float_as_uint(f);
    return (u16)((u + 0x7fffu + ((u >> 16) & 1u)) >> 16);
}
__device__ __forceinline__ unsigned pk2(float a, float b) {
    return (unsigned)f2bf(a) | ((unsigned)f2bf(b) << 16);
}

// ---------------- CSR build: histogram ----------------
__global__ void aml_hist_k(const int* __restrict__ ei, int* __restrict__ deg) {
    int e = blockIdx.x * 256 + threadIdx.x;
    if (e < EE) atomicAdd(&deg[ei[EE + e]], 1);
}

// ---------------- CSR build: exclusive scan ----------------
__global__ void aml_scan_k(const int* __restrict__ deg, int* __restrict__ rowptr,
                           int* __restrict__ cursor) {
    int t = threadIdx.x;
    int base = t * 24;
    int loc[24];
    int s = 0;
    #pragma unroll
    for (int j = 0; j < 24; ++j) { loc[j] = s; s += deg[base + j]; }
    __shared__ int part[256];
    part[t] = s;
    __syncthreads();
    for (int o = 1; o < 256; o <<= 1) {
        int v = (t >= o) ? part[t - o] : 0;
        __syncthreads();
        part[t] += v;
        __syncthreads();
    }
    int off = (t > 0) ? part[t - 1] : 0;
    #pragma unroll
    for (int j = 0; j < 24; ++j) {
        rowptr[base + j] = off + loc[j];
        cursor[base + j] = off + loc[j];
    }
    if (t == 255) rowptr[NN] = part[255];
}

// ---------------- CSR build: scatter edge sources ----------------
__global__ void aml_scatter2_k(const int* __restrict__ ei, int* __restrict__ cursor,
                               int* __restrict__ eid) {
    int e = blockIdx.x * 256 + threadIdx.x;
    if (e >= EE) return;
    int slot = atomicAdd(&cursor[ei[EE + e]], 1);
    eid[slot] = ei[e];
}

// ---------------- gather-mean + concat -> bf16 ac ----------------
__global__ void aml_gather_k(const float* __restrict__ x, const int* __restrict__ rowptr,
                             const int* __restrict__ eid, u16* __restrict__ ac) {
    int node = blockIdx.x * 4 + (threadIdx.x >> 6);
    int lane = threadIdx.x & 63;
    int p0 = rowptr[node], p1 = rowptr[node + 1];
    float ax = 0.f, ay = 0.f;
    int j = p0;
    for (; j + 1 < p1; j += 2) {
        int s0 = eid[j], s1 = eid[j + 1];
        float2 v0 = *(const float2*)(x + (size_t)s0 * DIN + lane * 2);
        float2 v1 = *(const float2*)(x + (size_t)s1 * DIN + lane * 2);
        ax += v0.x + v1.x; ay += v0.y + v1.y;
    }
    if (j < p1) {
        float2 v = *(const float2*)(x + (size_t)eid[j] * DIN + lane * 2);
        ax += v.x; ay += v.y;
    }
    float inv = 1.0f / fmaxf((float)(p1 - p0), 1.0f);
    float2 xr = *(const float2*)(x + (size_t)node * DIN + lane * 2);
    *(unsigned*)(ac + (size_t)node * DD + lane * 2) = pk2(ax * inv, ay * inv);
    *(unsigned*)(ac + (size_t)node * DD + DIN + lane * 2) = pk2(xr.x, xr.y);
}

// ---------------- prep: all weights -> bf16 rows [WROWS][256]; + segment offsets ----------------
__global__ void aml_prep_k(const float* __restrict__ lin_l_w, const float* __restrict__ lin_r_w,
                           const float* __restrict__ inp_w, const float* __restrict__ out_w,
                           const float* __restrict__ ff1_w, const float* __restrict__ ff2_w,
                           const int* __restrict__ ts, u16* __restrict__ wb,
                           int* __restrict__ offs) {
    int r = blockIdx.x;
    if (r == WROWS) {
        int t = threadIdx.x;
        if (t <= TT) {
            int lo = 0, hi = NN;
            while (lo < hi) { int mid = (lo + hi) >> 1; if (ts[mid] < t) lo = mid + 1; else hi = mid; }
            offs[t] = lo;
        }
        return;
    }
    int k = threadIdx.x;
    float v;
    if (r < 256) {
        v = (k < DIN) ? lin_l_w[r * DIN + k] : lin_r_w[r * DIN + (k - DIN)];
    } else {
        int r2 = r - 256;
        int l = r2 / 1536, r3 = r2 % 1536;
        const float* src; int rr;
        if (r3 < 768)       { src = inp_w + (size_t)l * 768 * DD; rr = r3; }
        else if (r3 < 1024) { src = out_w + (size_t)l * DD * DD;  rr = r3 - 768; }
        else if (r3 < 1280) { src = ff1_w + (size_t)l * DD * DD;  rr = r3 - 1024; }
        else                { src = ff2_w + (size_t)l * DD * DD;  rr = r3 - 1280; }
        v = src[(size_t)rr * DD + k];
    }
    wb[(size_t)r * DD + k] = f2bf(v);
}

// ---------------- MFMA GEMM: 64x64 tile, 4 waves, LDS-staged ----------------
// AF32: A f32 (pk2 staging) else bf16 copy. CF32: f32 out else bf16. RELU.
// BNSTAT: atomicAdd per-column sum/sumsq partials into stats (for BatchNorm).
template <int RELU, int AF32, int CF32, int BNSTAT>
__global__ __launch_bounds__(256)
void aml_gemm_k(const void* __restrict__ A, const u16* __restrict__ Wb,
                const float* __restrict__ bias, void* __restrict__ C, int M,
                float* __restrict__ stats) {
    __shared__ __align__(16) unsigned char lds[65536];
    const int t = threadIdx.x;
    const int brow = blockIdx.x * 64;
    const int bcol = blockIdx.y * 64;

    const u16* srcW = Wb + (size_t)bcol * 256;
    #pragma unroll
    for (int p = 0; p < 8; ++p) {
        int c = t + p * 256;
        int row = c >> 5;
        int colb = (c & 31) * 16;
        int dst = row * 512 + (colb ^ ((row & 7) << 4));
        if (AF32) {
            const float* sA = (const float*)A + (size_t)(brow + row) * 256 + (c & 31) * 8;
            float4 a0 = *(const float4*)sA;
            float4 a1 = *(const float4*)(sA + 4);
            uint4 pa = { pk2(a0.x, a0.y), pk2(a0.z, a0.w), pk2(a1.x, a1.y), pk2(a1.z, a1.w) };
            *(uint4*)(lds + dst) = pa;
        } else {
            const u16* sA = (const u16*)A + (size_t)(brow + row) * 256 + (c & 31) * 8;
            *(uint4*)(lds + dst) = *(const uint4*)sA;
        }
        *(uint4*)(lds + 32768 + dst) = *(const uint4*)(srcW + (size_t)row * 256 + (c & 31) * 8);
    }
    __syncthreads();

    const int wave = t >> 6, lane = t & 63;
    const int lrow = lane & 15, lk = lane >> 4;
    const int arow = wave * 16 + lrow;
    f32x4 acc[4] = {};
    #pragma unroll
    for (int ks = 0; ks < 8; ++ks) {
        int kbyte = ks * 64 + lk * 16;
        short8 af = *(const short8*)(lds + arow * 512 + (kbyte ^ ((arow & 7) << 4)));
        #pragma unroll
        for (int ct = 0; ct < 4; ++ct) {
            int wrow = ct * 16 + lrow;
            short8 bf = *(const short8*)(lds + 32768 + wrow * 512 + (kbyte ^ ((wrow & 7) << 4)));
            acc[ct] = __builtin_amdgcn_mfma_f32_16x16x32_bf16(af, bf, acc[ct], 0, 0, 0);
        }
    }

    #pragma unroll
    for (int ct = 0; ct < 4; ++ct) {
        int col = bcol + ct * 16 + lrow;
        float bv = bias[col];
        float s = 0.f, q = 0.f;
        #pragma unroll
        for (int r = 0; r < 4; ++r) {
            int grow = brow + wave * 16 + lk * 4 + r;
            float v = acc[ct][r] + bv;
            if (RELU) v = fmaxf(v, 0.0f);
            if (CF32) ((float*)C)[(size_t)grow * M + col] = v;
            else      ((u16*)C)[(size_t)grow * M + col] = f2bf(v);
            if (BNSTAT) { s += v; q += v * v; }
        }
        if (BNSTAT) {
            s += __shfl_xor(s, 16); s += __shfl_xor(s, 32);
            q += __shfl_xor(q, 16); q += __shfl_xor(q, 32);
            if (lk == 0) {
                atomicAdd(&stats[col], s);
                atomicAdd(&stats[DD + col], q);
            }
        }
    }
}

__global__ void aml_bn_apply_k(float* __restrict__ h, const float* __restrict__ stats,
                               const float* __restrict__ g, const float* __restrict__ b) {
    int idx = blockIdx.x * 256 + threadIdx.x;
    int d = idx & (DD - 1);
    float mu = stats[d] * (1.0f / NN);
    float var = stats[DD + d] * (1.0f / NN) - mu * mu;
    float v = (h[idx] - mu) * rsqrtf(var + 1e-5f) * g[d] + b[d];
    h[idx] = fmaxf(v, 0.0f);
}

// ---------------- fused GEMM + bias + residual(h) + LayerNorm [+ classifier] ----------------
// 64 rows x 256 cols per block; 4 waves; wave owns 16 FULL rows -> in-wave LN.
// A bf16 [NN][256]; W tiles staged per 64-col iteration; writes h (f32).
template <int CLS>
__global__ __launch_bounds__(256)
void aml_mega_k(const u16* __restrict__ A, const u16* __restrict__ Wb,
                const float* __restrict__ bias, float* __restrict__ h,
                const float* __restrict__ g, const float* __restrict__ bv,
                const float* __restrict__ cls_w, const float* __restrict__ cls_b,
                float* __restrict__ out) {
    __shared__ __align__(16) unsigned char lds[65536];  // A: [0,32K) W: [32K,64K)
    const int t = threadIdx.x;
    const int brow = blockIdx.x * 64;

    // stage A (bf16 copy, swizzled)
    #pragma unroll
    for (int p = 0; p < 8; ++p) {
        int c = t + p * 256;
        int row = c >> 5;
        int colb = (c & 31) * 16;
        int dst = row * 512 + (colb ^ ((row & 7) << 4));
        const u16* sA = A + (size_t)(brow + row) * 256 + (c & 31) * 8;
        *(uint4*)(lds + dst) = *(const uint4*)sA;
    }
    // stage W tile 0
    #pragma unroll
    for (int p = 0; p < 8; ++p) {
        int c = t + p * 256;
        int row = c >> 5;
        int colb = (c & 31) * 16;
        int dst = 32768 + row * 512 + (colb ^ ((row & 7) << 4));
        *(uint4*)(lds + dst) = *(const uint4*)(Wb + (size_t)row * 256 + (c & 31) * 8);
    }
    __syncthreads();

    const int wave = t >> 6, lane = t & 63;
    const int lrow = lane & 15, lk = lane >> 4;
    const int arow = wave * 16 + lrow;

    // hoist A fragments
    short8 af[8];
    #pragma unroll
    for (int ks = 0; ks < 8; ++ks) {
        int kbyte = ks * 64 + lk * 16;
        af[ks] = *(const short8*)(lds + arow * 512 + (kbyte ^ ((arow & 7) << 4)));
    }

    f32x4 acc[4][4] = {};
    for (int cT = 0; cT < 4; ++cT) {
        if (cT) {
            __syncthreads();  // all waves done reading previous W tile
            #pragma unroll
            for (int p = 0; p < 8; ++p) {
                int c = t + p * 256;
                int row = c >> 5;
                int colb = (c & 31) * 16;
                int dst = 32768 + row * 512 + (colb ^ ((row & 7) << 4));
                *(uint4*)(lds + dst) = *(const uint4*)(Wb + (size_t)(cT * 64 + row) * 256 + (c & 31) * 8);
            }
            __syncthreads();
        }
        #pragma unroll
        for (int ks = 0; ks < 8; ++ks) {
            int kbyte = ks * 64 + lk * 16;
            #pragma unroll
            for (int ct = 0; ct < 4; ++ct) {
                int wrow = ct * 16 + lrow;
                short8 bf = *(const short8*)(lds + 32768 + wrow * 512 + (kbyte ^ ((wrow & 7) << 4)));
                acc[cT][ct] = __builtin_amdgcn_mfma_f32_16x16x32_bf16(af[ks], bf, acc[cT][ct], 0, 0, 0);
            }
        }
    }

    // epilogue: bias + residual, row stats (wave owns full rows)
    float s[4] = {}, q[4] = {};
    #pragma unroll
    for (int cT = 0; cT < 4; ++cT) {
        #pragma unroll
        for (int ct = 0; ct < 4; ++ct) {
            int col = cT * 64 + ct * 16 + lrow;
            float bvv = bias[col];
            #pragma unroll
            for (int r = 0; r < 4; ++r) {
                int grow = brow + wave * 16 + lk * 4 + r;
                float v = acc[cT][ct][r] + bvv + h[(size_t)grow * DD + col];
                acc[cT][ct][r] = v;
                s[r] += v; q[r] += v * v;
            }
        }
    }
    #pragma unroll
    for (int off = 1; off < 16; off <<= 1) {
        #pragma unroll
        for (int r = 0; r < 4; ++r) {
            s[r] += __shfl_xor(s[r], off);
            q[r] += __shfl_xor(q[r], off);
        }
    }
    float mu[4], iv[4];
    #pragma unroll
    for (int r = 0; r < 4; ++r) {
        mu[r] = s[r] * (1.0f / DD);
        iv[r] = rsqrtf(q[r] * (1.0f / DD) - mu[r] * mu[r] + 1e-5f);
    }
    float c0[4] = {}, c1[4] = {};
    #pragma unroll
    for (int cT = 0; cT < 4; ++cT) {
        #pragma unroll
        for (int ct = 0; ct < 4; ++ct) {
            int col = cT * 64 + ct * 16 + lrow;
            float gv = g[col], bb = bv[col];
            float w0 = CLS ? cls_w[col] : 0.f;
            float w1 = CLS ? cls_w[DD + col] : 0.f;
            #pragma unroll
            for (int r = 0; r < 4; ++r) {
                int grow = brow + wave * 16 + lk * 4 + r;
                float v = (acc[cT][ct][r] - mu[r]) * iv[r] * gv + bb;
                h[(size_t)grow * DD + col] = v;
                if (CLS) { c0[r] += v * w0; c1[r] += v * w1; }
            }
        }
    }
    if (CLS) {
        #pragma unroll
        for (int off = 1; off < 16; off <<= 1) {
            #pragma unroll
            for (int r = 0; r < 4; ++r) {
                c0[r] += __shfl_xor(c0[r], off);
                c1[r] += __shfl_xor(c1[r], off);
            }
        }
        if (lrow == 0) {
            float cb0 = cls_b[0], cb1 = cls_b[1];
            #pragma unroll
            for (int r = 0; r < 4; ++r) {
                int grow = brow + wave * 16 + lk * 4 + r;
                out[grow * 2]     = c0[r] + cb0;
                out[grow * 2 + 1] = c1[r] + cb1;
            }
        }
    }
}

// ---------------- MFMA flash attention (bf16 qkv in, bf16 out) ----------------
__global__ __launch_bounds__(256)
void aml_attn_k(const u16* __restrict__ qkv, const int* __restrict__ offs,
                u16* __restrict__ o) {
    int tb = blockIdx.x, head = blockIdx.y, z = blockIdx.z;
    int start = offs[tb], end = offs[tb + 1];
    int S = end - start;
    if (S <= z * 64) return;
    int t = threadIdx.x, wave = t >> 6, lane = t & 63;
    int lq = lane & 15, lk = lane >> 4;
    int qoff = head * 64;

    __shared__ __align__(16) unsigned char Kl[8192];
    __shared__ __align__(16) unsigned char Vt[8192];
    __shared__ __align__(16) unsigned char Pl[4][2048];
    __shared__ float Ol[4][16][65];

    int qi = start + z * 64 + wave * 16 + lq;
    int qic = min(qi, end - 1);
    const u16* qp = qkv + (size_t)qic * 768 + qoff + lk * 8;
    short8 qf[2];
    qf[0] = *(const short8*)qp;
    qf[1] = *(const short8*)(qp + 32);

    float m = -1e30f, l = 0.f;
    f32x4 acc[4] = {};

    int ntile = (S + 63) >> 6;
    for (int tile = 0; tile < ntile; ++tile) {
        int jcnt = S - tile * 64; if (jcnt > 64) jcnt = 64;
        {
            int j = t >> 2, d0 = (t & 3) * 16;
            unsigned char* krow = Kl + j * 128;
            if (j < jcnt) {
                const u16* kp = qkv + (size_t)(start + tile * 64 + j) * 768 + 256 + qoff + d0;
                *(uint4*)(krow + ((d0 * 2) ^ ((j & 7) << 4))) = *(const uint4*)kp;
                *(uint4*)(krow + ((d0 * 2 + 16) ^ ((j & 7) << 4))) = *(const uint4*)(kp + 8);
                const u16* vp = kp + 256;
                #pragma unroll
                for (int i = 0; i < 16; ++i) {
                    int d = d0 + i;
                    *(u16*)(Vt + d * 128 + ((j * 2) ^ ((d & 7) << 4))) = vp[i];
                }
            } else {
                uint4 zz = { 0, 0, 0, 0 };
                *(uint4*)(krow + ((d0 * 2) ^ ((j & 7) << 4))) = zz;
                *(uint4*)(krow + ((d0 * 2 + 16) ^ ((j & 7) << 4))) = zz;
                #pragma unroll
                for (int i = 0; i < 16; ++i) {
                    int d = d0 + i;
                    *(u16*)(Vt + d * 128 + ((j * 2) ^ ((d & 7) << 4))) = 0;
                }
            }
        }
        __syncthreads();

        f32x4 sv[4];
        #pragma unroll
        for (int kt = 0; kt < 4; ++kt) {
            int kr = kt * 16 + lq;
            f32x4 s = {};
            #pragma unroll
            for (int ks = 0; ks < 2; ++ks) {
                short8 kf = *(const short8*)(Kl + kr * 128 + ((ks * 64 + lk * 16) ^ ((kr & 7) << 4)));
                s = __builtin_amdgcn_mfma_f32_16x16x32_bf16(kf, qf[ks], s, 0, 0, 0);
            }
            sv[kt] = s;
        }
        float pm = -1e30f;
        #pragma unroll
        for (int kt = 0; kt < 4; ++kt) {
            #pragma unroll
            for (int r = 0; r < 4; ++r) {
                int kk = tile * 64 + kt * 16 + lk * 4 + r;
                float s = (kk < S) ? sv[kt][r] * 0.125f : -1e30f;
                sv[kt][r] = s;
                pm = fmaxf(pm, s);
            }
        }
        pm = fmaxf(pm, __shfl_xor(pm, 16));
        pm = fmaxf(pm, __shfl_xor(pm, 32));
        float mn = fmaxf(m, pm);
        float corr = __expf(m - mn);
        m = mn;
        float ps = 0.f;
        #pragma unroll
        for (int kt = 0; kt < 4; ++kt) {
            #pragma unroll
            for (int r = 0; r < 4; ++r) {
                float p = __expf(sv[kt][r] - mn);
                sv[kt][r] = p;
                ps += p;
            }
            uint2 w = { pk2(sv[kt][0], sv[kt][1]), pk2(sv[kt][2], sv[kt][3]) };
            *(uint2*)(Pl[wave] + lq * 128 + ((kt * 32 + lk * 8) ^ ((lq & 7) << 4))) = w;
        }
        ps += __shfl_xor(ps, 16);
        ps += __shfl_xor(ps, 32);
        l = l * corr + ps;
        #pragma unroll
        for (int dt = 0; dt < 4; ++dt) {
            #pragma unroll
            for (int r = 0; r < 4; ++r) acc[dt][r] *= corr;
        }
        #pragma unroll
        for (int ks = 0; ks < 2; ++ks) {
            short8 pf = *(const short8*)(Pl[wave] + lq * 128 + ((ks * 64 + lk * 16) ^ ((lq & 7) << 4)));
            #pragma unroll
            for (int dt = 0; dt < 4; ++dt) {
                int dr = dt * 16 + lq;
                short8 vf = *(const short8*)(Vt + dr * 128 + ((ks * 64 + lk * 16) ^ ((dr & 7) << 4)));
                acc[dt] = __builtin_amdgcn_mfma_f32_16x16x32_bf16(vf, pf, acc[dt], 0, 0, 0);
            }
        }
        __syncthreads();
    }

    float linv = 1.0f / l;
    #pragma unroll
    for (int dt = 0; dt < 4; ++dt) {
        #pragma unroll
        for (int r = 0; r < 4; ++r)
            Ol[wave][lq][dt * 16 + lk * 4 + r] = acc[dt][r] * linv;
    }
    int q2 = lane >> 2, c2 = lane & 3;
    int qg = start + z * 64 + wave * 16 + q2;
    if (qg < end) {
        u16* op = o + (size_t)qg * DD + qoff + c2 * 16;
        const float* sp = &Ol[wave][q2][c2 * 16];
        #pragma unroll
        for (int i = 0; i < 8; ++i)
            ((unsigned*)op)[i] = pk2(sp[2 * i], sp[2 * i + 1]);
    }
}

extern "C" void kernel_launch(void* const* d_in, const int* in_sizes, int n_in,
                              void* d_out, int out_size, void* d_ws, size_t ws_size,
                              hipStream_t stream) {
    const float* x       = (const float*)d_in[0];
    const int*   ei      = (const int*)d_in[1];
    const int*   ts      = (const int*)d_in[2];
    const float* lin_l_w = (const float*)d_in[3];
    const float* lin_l_b = (const float*)d_in[4];
    const float* lin_r_w = (const float*)d_in[5];
    const float* bn_g    = (const float*)d_in[6];
    const float* bn_b    = (const float*)d_in[7];
    const float* inp_w   = (const float*)d_in[8];
    const float* inp_b   = (const float*)d_in[9];
    const float* out_w   = (const float*)d_in[10];
    const float* out_b   = (const float*)d_in[11];
    const float* ff1_w   = (const float*)d_in[12];
    const float* ff1_b   = (const float*)d_in[13];
    const float* ff2_w   = (const float*)d_in[14];
    const float* ff2_b   = (const float*)d_in[15];
    const float* ln1_g   = (const float*)d_in[16];
    const float* ln1_b   = (const float*)d_in[17];
    const float* ln2_g   = (const float*)d_in[18];
    const float* ln2_b   = (const float*)d_in[19];
    const float* cls_w   = (const float*)d_in[20];
    const float* cls_b   = (const float*)d_in[21];

    float* ws     = (float*)d_ws;
    float* stats  = ws;                          // 512 f32 (zeroed)
    int*   deg    = (int*)(stats + 512);         // NN (zeroed)
    int*   rowptr = deg + NN;                    // NN+4 (padded)
    int*   cursor = rowptr + NN + 4;             // NN
    int*   eid    = cursor + NN;                 // EE
    int*   offs   = eid + EE;                    // 64
    u16*   wb     = (u16*)(offs + 64);           // WROWS*256 bf16
    float* h      = (float*)(wb + (size_t)WROWS * 256);  // N*256 f32
    u16*   qkv    = (u16*)(h + (size_t)NN * DD); // N*768 bf16
    u16*   t1     = qkv + (size_t)NN * 768;      // N*256 bf16
    u16*   ac     = qkv;                         // alias (consumed before qkv written)

    const u16* wb_cat = wb;
    const u16* wb_inp[2] = { wb + (size_t)(256) * 256,        wb + (size_t)(256 + 1536) * 256 };
    const u16* wb_out[2] = { wb + (size_t)(256 + 768) * 256,  wb + (size_t)(256 + 1536 + 768) * 256 };
    const u16* wb_ff1[2] = { wb + (size_t)(256 + 1024) * 256, wb + (size_t)(256 + 1536 + 1024) * 256 };
    const u16* wb_ff2[2] = { wb + (size_t)(256 + 1280) * 256, wb + (size_t)(256 + 1536 + 1280) * 256 };

    hipMemsetAsync(stats, 0, 512 * sizeof(float) + NN * sizeof(int), stream);

    aml_hist_k<<<EE / 256, 256, 0, stream>>>(ei, deg);
    aml_scan_k<<<1, 256, 0, stream>>>(deg, rowptr, cursor);
    aml_scatter2_k<<<EE / 256, 256, 0, stream>>>(ei, cursor, eid);
    aml_gather_k<<<NN / 4, 256, 0, stream>>>(x, rowptr, eid, ac);
    aml_prep_k<<<WROWS + 1, 256, 0, stream>>>(lin_l_w, lin_r_w, inp_w, out_w, ff1_w, ff2_w,
                                              ts, wb, offs);
    // SAGE: ac(bf16) x wcat -> h(f32), fused BN column stats
    aml_gemm_k<0, 0, 1, 1><<<dim3(NN / 64, 4), 256, 0, stream>>>(ac, wb_cat, lin_l_b, h, DD, stats);
    aml_bn_apply_k<<<(NN * DD) / 256, 256, 0, stream>>>(h, stats, bn_g, bn_b);

    for (int l = 0; l < 2; ++l) {
        // qkv: h(f32) x inp_w -> qkv(bf16)
        aml_gemm_k<0, 1, 0, 0><<<dim3(NN / 64, 12), 256, 0, stream>>>(h, wb_inp[l],
                                                                      inp_b + (size_t)l * 768,
                                                                      qkv, 768, nullptr);
        aml_attn_k<<<dim3(TT, NH, ATTN_Z), 256, 0, stream>>>(qkv, offs, t1);
        // out-proj + residual + LN1 -> h
        aml_mega_k<0><<<NN / 64, 256, 0, stream>>>(t1, wb_out[l], out_b + (size_t)l * DD, h,
                                                   ln1_g + (size_t)l * DD, ln1_b + (size_t)l * DD,
                                                   nullptr, nullptr, nullptr);
        // ff1: h(f32) x ff1_w -> t1(bf16), ReLU
        aml_gemm_k<1, 1, 0, 0><<<dim3(NN / 64, 4), 256, 0, stream>>>(h, wb_ff1[l],
                                                                     ff1_b + (size_t)l * DD,
                                                                     t1, DD, nullptr);
        // ff2 + residual + LN2 -> h (+ classifier on last layer)
        if (l == 0)
            aml_mega_k<0><<<NN / 64, 256, 0, stream>>>(t1, wb_ff2[l], ff2_b + (size_t)l * DD, h,
                                                       ln2_g + (size_t)l * DD, ln2_b + (size_t)l * DD,
                                                       nullptr, nullptr, nullptr);
        else
            aml_mega_k<1><<<NN / 64, 256, 0, stream>>>(t1, wb_ff2[l], ff2_b + (size_t)l * DD, h,
                                                       ln2_g + (size_t)l * DD, ln2_b + (size_t)l * DD,
                                                       cls_w, cls_b, (float*)d_out);
    }
}